// Round 1
// baseline (1424.512 us; speedup 1.0000x reference)
//
#include <hip/hip_runtime.h>

// Problem: B=256, T=512, I=64, H=512.  h_t = tanh(x_t@Wxh + b + h@Whh); out = h_T@fc_w.T + fc_b
//
// rnn_quad mapping (this round's change): 1 batch row per block, 1024 threads.
//   thread = (q = tid&3 -> K-quarter [128q,128q+128), col pair jA=32*(tid>>6)+2*((tid>>2)&15), jB=jA+1)
//   Weights: 92 half2 in arch VGPRs (<=128 budget @ 4 waves/SIMD, no AGPR round-trips),
//            9 x 16B chunks/thread in LDS (thread-major stride 144B = optimal 8 acc/bank, imm offsets).
//   h buffer: fp16, 32B skew between K-quarter regions -> quad reads at banks 8q+4i, conflict-free,
//            single base reg + immediate offsets (zero per-step address VALU).
//   K-reduction: in-quad DPP quad_perm adds (VALU only), 1 barrier/step.
// Prev round (rnn_split, 512 thr, 2 waves/SIMD, 208-reg weight array -> AGPR spill) : 937us.

#define BATCH    256
#define TSTEPS   512
#define IDIM     64
#define HDIM     512
#define NTH      512

typedef _Float16 half2_t __attribute__((ext_vector_type(2)));
typedef _Float16 half8_t __attribute__((ext_vector_type(8)));

union H8U {
    half8_t v;
    half2_t p[4];
    uint4   u4;
};

__device__ __forceinline__ float fdot2(half2_t a, half2_t b, float c) {
#if __has_builtin(__builtin_amdgcn_fdot2)
    return __builtin_amdgcn_fdot2(a, b, c, false);
#else
    return c + (float)a[0] * (float)b[0] + (float)a[1] * (float)b[1];
#endif
}

__device__ __forceinline__ float fast_tanh(float x) {
    float e = __builtin_amdgcn_exp2f(x * 2.88539008177792681472f);
    return 1.0f - 2.0f * __builtin_amdgcn_rcpf(e + 1.0f);
}

// sum over the 4 lanes of each quad (q = lane&3), VALU-only (no LDS, no barrier)
__device__ __forceinline__ float quad_sum(float x) {
    union { float f; int i; } a, b;
    a.f = x;
    b.i = __builtin_amdgcn_update_dpp(0, a.i, 0xB1, 0xF, 0xF, true); // quad_perm [1,0,3,2]
    a.f += b.f;
    b.i = __builtin_amdgcn_update_dpp(0, a.i, 0x4E, 0xF, 0xF, true); // quad_perm [2,3,0,1]
    a.f += b.f;
    return a.f;
}

// ============================= xh precompute (unchanged this round) =============================
#define XH_ROWS 16
__global__ __launch_bounds__(NTH, 4)
void xh_gemm(const float* __restrict__ x, const float* __restrict__ Wxh,
             const float* __restrict__ bias, _Float16* __restrict__ xh)
{
    const int j = threadIdx.x;
    const size_t r0 = (size_t)blockIdx.x * XH_ROWS;
    float wcol[IDIM];
#pragma unroll
    for (int i = 0; i < IDIM; ++i) wcol[i] = Wxh[(size_t)i * HDIM + j];
    const float bj = bias[j];
#pragma unroll
    for (int r = 0; r < XH_ROWS; ++r) {
        const float* xr = x + (r0 + r) * IDIM;   // wave-uniform address -> s_loads
        float acc = bj;
#pragma unroll
        for (int i = 0; i < IDIM; ++i) acc += xr[i] * wcol[i];
        xh[(r0 + r) * HDIM + j] = (_Float16)acc;
    }
}

// ============================= quad-split RNN (K=512, 4-way K split) =============================
#define NTH2      1024
#define Q_CHUNKS  16            // 16 h-chunks of 8 rows per thread (K slice = 128)
#define Q_AREG    12            // colA: chunks 0..11 in regs, 12..15 in LDS (4 chunks)
#define Q_BREG    11            // colB: chunks 0..10 in regs, 11..15 in LDS (5 chunks)
#define Q_LCH     9             // LDS weight chunks per thread
#define Q_LDSW_BYTES (NTH2 * Q_LCH * 16)          // 147456
#define Q_HB_OFF     Q_LDSW_BYTES
#define Q_HB_STRIDE  1152                          // 1024B h data + 3x32B inter-region skew, padded
#define Q_RED_OFF    (Q_HB_OFF + 2 * Q_HB_STRIDE)  // 149760
#define Q_SMEM_BYTES (Q_RED_OFF + 64)              // 149824 (< 160 KiB)

__global__ __attribute__((amdgpu_flat_work_group_size(NTH2, NTH2)))
void rnn_quad(const _Float16* __restrict__ xh,   // (B*T, H) fp16, bias folded in
              const float* __restrict__ Whh,     // (H,H)
              const float* __restrict__ fcw,     // (1,H)
              const float* __restrict__ fcb,     // (1)
              float* __restrict__ out)           // (B,1)
{
    extern __shared__ char smem[];
    uint4* ldsW = reinterpret_cast<uint4*>(smem);
    float* red  = reinterpret_cast<float*>(smem + Q_RED_OFF);

    const int tid = threadIdx.x;
    const int q   = tid & 3;            // K-quarter
    const int co  = (tid >> 2) & 15;    // column pair within wave
    const int wv  = tid >> 6;           // wave id
    const int jA  = wv * 32 + co * 2;   // even column; jB = jA+1
    const int b   = blockIdx.x;

    // ---- prologue: columns jA,jA+1 of Whh, rows [128q, 128q+128), as fp16 (k,k+1) pairs ----
    half2_t wAr[4 * Q_AREG];            // 48 half2
    half2_t wBr[4 * Q_BREG];            // 44 half2
    uint4*  myW = ldsW + tid * Q_LCH;   // stride 144B -> 8 accesses/bank (optimal), imm offsets
#pragma unroll
    for (int i = 0; i < Q_CHUNKS; ++i) {
        H8U a, c;
#pragma unroll
        for (int e = 0; e < 4; ++e) {
            const int k = 128 * q + 8 * i + 2 * e;
            const float2 r0 = *reinterpret_cast<const float2*>(Whh + (size_t)k * HDIM + jA);
            const float2 r1 = *reinterpret_cast<const float2*>(Whh + (size_t)(k + 1) * HDIM + jA);
            half2_t ha; ha[0] = (_Float16)r0.x; ha[1] = (_Float16)r1.x;
            half2_t hc; hc[0] = (_Float16)r0.y; hc[1] = (_Float16)r1.y;
            if (i < Q_AREG) wAr[4 * i + e] = ha; else a.p[e] = ha;
            if (i < Q_BREG) wBr[4 * i + e] = hc; else c.p[e] = hc;
        }
        if (i >= Q_AREG) myW[i - Q_AREG]       = a.u4;   // cid 0..3
        if (i >= Q_BREG) myW[4 + (i - Q_BREG)] = c.u4;   // cid 4..8
    }

    // h buffers: region q starts at byte 288*q (256B data + 32B skew per region)
    const _Float16* hb0 = reinterpret_cast<const _Float16*>(smem + Q_HB_OFF + 288 * q);
    const _Float16* hb1 = reinterpret_cast<const _Float16*>(smem + Q_HB_OFF + Q_HB_STRIDE + 288 * q);
    // per-thread write slot (skewed to match)
    _Float16* wp0 = reinterpret_cast<_Float16*>(smem + Q_HB_OFF + 2 * jA + 32 * (jA >> 7));
    _Float16* wp1 = reinterpret_cast<_Float16*>(smem + Q_HB_OFF + Q_HB_STRIDE + 2 * jA + 32 * (jA >> 7));

    const float fcwA = fcw[jA];
    const float fcwB = fcw[jA + 1];
    const _Float16* xhp = xh + (size_t)b * TSTEPS * HDIM + jA;

    if (q == 0) {   // h_0 = 0 into buffer 0
        half2_t z; z[0] = (_Float16)0.f; z[1] = (_Float16)0.f;
        *reinterpret_cast<half2_t*>(wp0) = z;
    }
    __syncthreads();

    float hA = 0.f, hB = 0.f;
#pragma unroll 1
    for (int t = 0; t < TSTEPS; ++t) {
        const _Float16* hb = (t & 1) ? hb1 : hb0;
        const half2_t xv = *reinterpret_cast<const half2_t*>(xhp);   // xh[t][jA], xh[t][jB]
        xhp += HDIM;

        float a0 = 0.f, a1 = 0.f, c0 = 0.f, c1 = 0.f;
#pragma unroll
        for (int i = 0; i < Q_BREG; ++i) {          // chunks 0..10: both cols from regs
            H8U u; u.v = *reinterpret_cast<const half8_t*>(hb + 8 * i);
            a0 = fdot2(u.p[0], wAr[4*i+0], a0);
            a1 = fdot2(u.p[1], wAr[4*i+1], a1);
            a0 = fdot2(u.p[2], wAr[4*i+2], a0);
            a1 = fdot2(u.p[3], wAr[4*i+3], a1);
            c0 = fdot2(u.p[0], wBr[4*i+0], c0);
            c1 = fdot2(u.p[1], wBr[4*i+1], c1);
            c0 = fdot2(u.p[2], wBr[4*i+2], c0);
            c1 = fdot2(u.p[3], wBr[4*i+3], c1);
        }
        {   // chunk 11: A from regs, B from LDS cid 4
            H8U u; u.v = *reinterpret_cast<const half8_t*>(hb + 8 * 11);
            H8U wc; wc.u4 = myW[4];
            a0 = fdot2(u.p[0], wAr[44], a0);
            a1 = fdot2(u.p[1], wAr[45], a1);
            a0 = fdot2(u.p[2], wAr[46], a0);
            a1 = fdot2(u.p[3], wAr[47], a1);
            c0 = fdot2(u.p[0], wc.p[0], c0);
            c1 = fdot2(u.p[1], wc.p[1], c1);
            c0 = fdot2(u.p[2], wc.p[2], c0);
            c1 = fdot2(u.p[3], wc.p[3], c1);
        }
#pragma unroll
        for (int i = 12; i < 16; ++i) {             // chunks 12..15: A cid i-12, B cid i-7
            H8U u; u.v = *reinterpret_cast<const half8_t*>(hb + 8 * i);
            H8U wa; wa.u4 = myW[i - 12];
            H8U wc; wc.u4 = myW[i - 7];
            a0 = fdot2(u.p[0], wa.p[0], a0);
            a1 = fdot2(u.p[1], wa.p[1], a1);
            a0 = fdot2(u.p[2], wa.p[2], a0);
            a1 = fdot2(u.p[3], wa.p[3], a1);
            c0 = fdot2(u.p[0], wc.p[0], c0);
            c1 = fdot2(u.p[1], wc.p[1], c1);
            c0 = fdot2(u.p[2], wc.p[2], c0);
            c1 = fdot2(u.p[3], wc.p[3], c1);
        }

        const float sA = quad_sum(a0 + a1);
        const float sB = quad_sum(c0 + c1);

        if (q == 0) {
            hA = fast_tanh(sA + (float)xv[0]);
            hB = fast_tanh(sB + (float)xv[1]);
            half2_t hw; hw[0] = (_Float16)hA; hw[1] = (_Float16)hB;
            *reinterpret_cast<half2_t*>((t & 1) ? wp0 : wp1) = hw;   // write buffer (t+1)&1
        }
        __syncthreads();
    }

    // ---- Epilogue: out[b] = sum_j h_j * fcw_j + fcb ----
    float partial = (q == 0) ? (hA * fcwA + hB * fcwB) : 0.f;
#pragma unroll
    for (int off = 32; off >= 1; off >>= 1)
        partial += __shfl_down(partial, off, 64);
    if ((tid & 63) == 0) red[tid >> 6] = partial;
    __syncthreads();
    if (tid == 0) {
        float s = 0.f;
#pragma unroll
        for (int w = 0; w < 16; ++w) s += red[w];
        out[b] = s + fcb[0];
    }
}

// ============================= fused fallback (K=576, unchanged) =============================
#define F_RP   216          // reg pairs: k in [0,432)
#define F_RC   54
#define F_LC   18           // LDS chunks: k in [432,576)
#define F_LSTR 19
#define F_LDSW_BYTES (512 * F_LSTR * 16)          // 155648
#define F_HBUF_OFF   F_LDSW_BYTES
#define F_HBUF_ELEMS 640                          // [0,512)=h, [512,576)=x_t
#define F_RED_OFF    (F_HBUF_OFF + 2 * F_HBUF_ELEMS * 2)
#define F_SMEM_BYTES (F_RED_OFF + 64)             // ~158.2 KB

__global__ __attribute__((amdgpu_flat_work_group_size(NTH, NTH), amdgpu_waves_per_eu(2, 2)))
void rnn_fused(const float* __restrict__ x, const float* __restrict__ Wxh,
               const float* __restrict__ Whh, const float* __restrict__ bias,
               const float* __restrict__ fcw, const float* __restrict__ fcb,
               float* __restrict__ out)
{
    extern __shared__ char smem[];
    uint4*    ldsW = reinterpret_cast<uint4*>(smem);
    _Float16* hbuf = reinterpret_cast<_Float16*>(smem + F_HBUF_OFF);
    float*    red  = reinterpret_cast<float*>(smem + F_RED_OFF);

    const int j = threadIdx.x;
    const int b = blockIdx.x;

    half2_t wreg[F_RP];
#pragma unroll
    for (int p = 0; p < F_RP; ++p) {
        const int k = 2 * p;
        half2_t w;
        w[0] = (_Float16)Whh[(size_t)k * HDIM + j];
        w[1] = (_Float16)Whh[(size_t)(k + 1) * HDIM + j];
        wreg[p] = w;
    }
#pragma unroll
    for (int cc = 0; cc < F_LC; ++cc) {
        H8U u;
#pragma unroll
        for (int qq = 0; qq < 4; ++qq) {
            const int k0 = 432 + 8 * cc + 2 * qq;
            const int k1 = k0 + 1;
            half2_t w;
            w[0] = (_Float16)(k0 < HDIM ? Whh[(size_t)k0 * HDIM + j]
                                        : Wxh[(size_t)(k0 - HDIM) * HDIM + j]);
            w[1] = (_Float16)(k1 < HDIM ? Whh[(size_t)k1 * HDIM + j]
                                        : Wxh[(size_t)(k1 - HDIM) * HDIM + j]);
            u.p[qq] = w;
        }
        ldsW[j * F_LSTR + cc] = u.u4;
    }

    const float bj   = bias[j];
    const float fcwj = fcw[j];

    hbuf[j] = (_Float16)0.0f;
    if (j < IDIM) hbuf[HDIM + j] = (_Float16)x[((size_t)b * TSTEPS + 0) * IDIM + j];
    __syncthreads();

    float hval = 0.0f;
    for (int t = 0; t < TSTEPS; ++t) {
        const int cur = t & 1;
        const int nxt = cur ^ 1;
        const _Float16* hb = hbuf + cur * F_HBUF_ELEMS;

        float xv = 0.0f;
        const bool do_x = (j < IDIM) && (t + 1 < TSTEPS);
        if (do_x) xv = x[((size_t)b * TSTEPS + (t + 1)) * IDIM + j];

        float a0 = bj, a1 = 0.0f, a2 = 0.0f, a3 = 0.0f;
#pragma unroll
        for (int c = 0; c < F_RC; ++c) {
            H8U u;
            u.v = *reinterpret_cast<const half8_t*>(hb + 8 * c);
            a0 = fdot2(u.p[0], wreg[4 * c + 0], a0);
            a1 = fdot2(u.p[1], wreg[4 * c + 1], a1);
            a2 = fdot2(u.p[2], wreg[4 * c + 2], a2);
            a3 = fdot2(u.p[3], wreg[4 * c + 3], a3);
        }
#pragma unroll
        for (int cc = 0; cc < F_LC; ++cc) {
            H8U u, w;
            u.v  = *reinterpret_cast<const half8_t*>(hb + 8 * (F_RC + cc));
            w.u4 = ldsW[j * F_LSTR + cc];
            a0 = fdot2(u.p[0], w.p[0], a0);
            a1 = fdot2(u.p[1], w.p[1], a1);
            a2 = fdot2(u.p[2], w.p[2], a2);
            a3 = fdot2(u.p[3], w.p[3], a3);
        }
        hval = fast_tanh((a0 + a1) + (a2 + a3));

        hbuf[nxt * F_HBUF_ELEMS + j] = (_Float16)hval;
        if (do_x) hbuf[nxt * F_HBUF_ELEMS + HDIM + j] = (_Float16)xv;
        __syncthreads();
    }

    float partial = hval * fcwj;
#pragma unroll
    for (int off = 32; off >= 1; off >>= 1)
        partial += __shfl_down(partial, off, 64);
    if ((j & 63) == 0) red[j >> 6] = partial;
    __syncthreads();
    if (j == 0) {
        float s = 0.0f;
#pragma unroll
        for (int w = 0; w < 8; ++w) s += red[w];
        out[b] = s + fcb[0];
    }
}

// ============================= host =============================
extern "C" void kernel_launch(void* const* d_in, const int* in_sizes, int n_in,
                              void* d_out, int out_size, void* d_ws, size_t ws_size,
                              hipStream_t stream) {
    const float* x    = (const float*)d_in[0];
    const float* Wxh  = (const float*)d_in[1];
    const float* Whh  = (const float*)d_in[2];
    const float* bias = (const float*)d_in[3];
    const float* fcw  = (const float*)d_in[4];
    const float* fcb  = (const float*)d_in[5];
    float* out = (float*)d_out;

    const size_t xh_bytes = (size_t)BATCH * TSTEPS * HDIM * sizeof(_Float16);  // 134 MB
    if (ws_size >= xh_bytes) {
        hipFuncSetAttribute(reinterpret_cast<const void*>(rnn_quad),
                            hipFuncAttributeMaxDynamicSharedMemorySize, Q_SMEM_BYTES);
        _Float16* xh = (_Float16*)d_ws;
        xh_gemm<<<(BATCH * TSTEPS) / XH_ROWS, NTH, 0, stream>>>(x, Wxh, bias, xh);
        rnn_quad<<<BATCH, NTH2, Q_SMEM_BYTES, stream>>>(xh, Whh, fcw, fcb, out);
    } else {
        hipFuncSetAttribute(reinterpret_cast<const void*>(rnn_fused),
                            hipFuncAttributeMaxDynamicSharedMemorySize, F_SMEM_BYTES);
        rnn_fused<<<BATCH, NTH, F_SMEM_BYTES, stream>>>(x, Wxh, Whh, bias, fcw, fcb, out);
    }
}

// Round 2
// 1387.894 us; speedup vs baseline: 1.0264x; 1.0264x over previous
//
#include <hip/hip_runtime.h>

// Problem: B=256, T=512, I=64, H=512.  h_t = tanh(x_t@Wxh + b + h@Whh); out = h_T@fc_w.T + fc_b
//
// rnn_quad mapping: 1 batch row per block, 1024 threads.
//   thread = (q = tid&3 -> K-quarter [128q,128q+128), col pair jA=32*(tid>>6)+2*((tid>>2)&15), jB=jA+1)
//   Weights: 92 half2 in arch VGPRs, 9 x 16B chunks/thread in LDS (stride 144B, imm offsets).
//   h buffer: fp16, 32B skew between K-quarter regions -> conflict-free quad reads, imm offsets.
//   K-reduction: in-quad DPP quad_perm adds, 1 barrier/step.
//
// Round-1 lesson: without waves_per_eu the compiler targeted 8 waves/EU -> VGPR_Count=64 and
// spilled all 92 weight VGPRs to scratch (WRITE_SIZE 98 MB == 92*4*1024*256 spill bytes).
// This round: amdgpu_waves_per_eu(4,4) pins the 128-VGPR budget the mapping was designed for
// (LDS 149.8 KB forces 1 block/CU = 4 waves/SIMD anyway, so 128 VGPRs costs no occupancy).

#define BATCH    256
#define TSTEPS   512
#define IDIM     64
#define HDIM     512
#define NTH      512

typedef _Float16 half2_t __attribute__((ext_vector_type(2)));
typedef _Float16 half8_t __attribute__((ext_vector_type(8)));

union H8U {
    half8_t v;
    half2_t p[4];
    uint4   u4;
};

__device__ __forceinline__ float fdot2(half2_t a, half2_t b, float c) {
#if __has_builtin(__builtin_amdgcn_fdot2)
    return __builtin_amdgcn_fdot2(a, b, c, false);
#else
    return c + (float)a[0] * (float)b[0] + (float)a[1] * (float)b[1];
#endif
}

__device__ __forceinline__ float fast_tanh(float x) {
    float e = __builtin_amdgcn_exp2f(x * 2.88539008177792681472f);
    return 1.0f - 2.0f * __builtin_amdgcn_rcpf(e + 1.0f);
}

// sum over the 4 lanes of each quad (q = lane&3), VALU-only (no LDS, no barrier)
__device__ __forceinline__ float quad_sum(float x) {
    union { float f; int i; } a, b;
    a.f = x;
    b.i = __builtin_amdgcn_update_dpp(0, a.i, 0xB1, 0xF, 0xF, true); // quad_perm [1,0,3,2]
    a.f += b.f;
    b.i = __builtin_amdgcn_update_dpp(0, a.i, 0x4E, 0xF, 0xF, true); // quad_perm [2,3,0,1]
    a.f += b.f;
    return a.f;
}

// ============================= xh precompute (unchanged this round) =============================
#define XH_ROWS 16
__global__ __launch_bounds__(NTH, 4)
void xh_gemm(const float* __restrict__ x, const float* __restrict__ Wxh,
             const float* __restrict__ bias, _Float16* __restrict__ xh)
{
    const int j = threadIdx.x;
    const size_t r0 = (size_t)blockIdx.x * XH_ROWS;
    float wcol[IDIM];
#pragma unroll
    for (int i = 0; i < IDIM; ++i) wcol[i] = Wxh[(size_t)i * HDIM + j];
    const float bj = bias[j];
#pragma unroll
    for (int r = 0; r < XH_ROWS; ++r) {
        const float* xr = x + (r0 + r) * IDIM;   // wave-uniform address -> s_loads
        float acc = bj;
#pragma unroll
        for (int i = 0; i < IDIM; ++i) acc += xr[i] * wcol[i];
        xh[(r0 + r) * HDIM + j] = (_Float16)acc;
    }
}

// ============================= quad-split RNN (K=512, 4-way K split) =============================
#define NTH2      1024
#define Q_CHUNKS  16            // 16 h-chunks of 8 rows per thread (K slice = 128)
#define Q_AREG    12            // colA: chunks 0..11 in regs, 12..15 in LDS (4 chunks)
#define Q_BREG    11            // colB: chunks 0..10 in regs, 11..15 in LDS (5 chunks)
#define Q_LCH     9             // LDS weight chunks per thread
#define Q_LDSW_BYTES (NTH2 * Q_LCH * 16)          // 147456
#define Q_HB_OFF     Q_LDSW_BYTES
#define Q_HB_STRIDE  1152                          // 1024B h data + 3x32B inter-region skew, padded
#define Q_RED_OFF    (Q_HB_OFF + 2 * Q_HB_STRIDE)  // 149760
#define Q_SMEM_BYTES (Q_RED_OFF + 64)              // 149824 (< 160 KiB)

__global__ __attribute__((amdgpu_flat_work_group_size(NTH2, NTH2), amdgpu_waves_per_eu(4, 4)))
void rnn_quad(const _Float16* __restrict__ xh,   // (B*T, H) fp16, bias folded in
              const float* __restrict__ Whh,     // (H,H)
              const float* __restrict__ fcw,     // (1,H)
              const float* __restrict__ fcb,     // (1)
              float* __restrict__ out)           // (B,1)
{
    extern __shared__ char smem[];
    uint4* ldsW = reinterpret_cast<uint4*>(smem);
    float* red  = reinterpret_cast<float*>(smem + Q_RED_OFF);

    const int tid = threadIdx.x;
    const int q   = tid & 3;            // K-quarter
    const int co  = (tid >> 2) & 15;    // column pair within wave
    const int wv  = tid >> 6;           // wave id
    const int jA  = wv * 32 + co * 2;   // even column; jB = jA+1
    const int b   = blockIdx.x;

    // ---- prologue: columns jA,jA+1 of Whh, rows [128q, 128q+128), as fp16 (k,k+1) pairs ----
    half2_t wAr[4 * Q_AREG];            // 48 half2
    half2_t wBr[4 * Q_BREG];            // 44 half2
    uint4*  myW = ldsW + tid * Q_LCH;   // stride 144B -> 8 accesses/bank (optimal), imm offsets
#pragma unroll
    for (int i = 0; i < Q_CHUNKS; ++i) {
        H8U a, c;
#pragma unroll
        for (int e = 0; e < 4; ++e) {
            const int k = 128 * q + 8 * i + 2 * e;
            const float2 r0 = *reinterpret_cast<const float2*>(Whh + (size_t)k * HDIM + jA);
            const float2 r1 = *reinterpret_cast<const float2*>(Whh + (size_t)(k + 1) * HDIM + jA);
            half2_t ha; ha[0] = (_Float16)r0.x; ha[1] = (_Float16)r1.x;
            half2_t hc; hc[0] = (_Float16)r0.y; hc[1] = (_Float16)r1.y;
            if (i < Q_AREG) wAr[4 * i + e] = ha; else a.p[e] = ha;
            if (i < Q_BREG) wBr[4 * i + e] = hc; else c.p[e] = hc;
        }
        if (i >= Q_AREG) myW[i - Q_AREG]       = a.u4;   // cid 0..3
        if (i >= Q_BREG) myW[4 + (i - Q_BREG)] = c.u4;   // cid 4..8
    }

    // h buffers: region q starts at byte 288*q (256B data + 32B skew per region)
    const _Float16* hb0 = reinterpret_cast<const _Float16*>(smem + Q_HB_OFF + 288 * q);
    const _Float16* hb1 = reinterpret_cast<const _Float16*>(smem + Q_HB_OFF + Q_HB_STRIDE + 288 * q);
    // per-thread write slot (skewed to match)
    _Float16* wp0 = reinterpret_cast<_Float16*>(smem + Q_HB_OFF + 2 * jA + 32 * (jA >> 7));
    _Float16* wp1 = reinterpret_cast<_Float16*>(smem + Q_HB_OFF + Q_HB_STRIDE + 2 * jA + 32 * (jA >> 7));

    const float fcwA = fcw[jA];
    const float fcwB = fcw[jA + 1];
    const _Float16* xhp = xh + (size_t)b * TSTEPS * HDIM + jA;

    if (q == 0) {   // h_0 = 0 into buffer 0
        half2_t z; z[0] = (_Float16)0.f; z[1] = (_Float16)0.f;
        *reinterpret_cast<half2_t*>(wp0) = z;
    }
    __syncthreads();

    float hA = 0.f, hB = 0.f;
#pragma unroll 1
    for (int t = 0; t < TSTEPS; ++t) {
        const _Float16* hb = (t & 1) ? hb1 : hb0;
        const half2_t xv = *reinterpret_cast<const half2_t*>(xhp);   // xh[t][jA], xh[t][jB]
        xhp += HDIM;

        float a0 = 0.f, a1 = 0.f, c0 = 0.f, c1 = 0.f;
#pragma unroll
        for (int i = 0; i < Q_BREG; ++i) {          // chunks 0..10: both cols from regs
            H8U u; u.v = *reinterpret_cast<const half8_t*>(hb + 8 * i);
            a0 = fdot2(u.p[0], wAr[4*i+0], a0);
            a1 = fdot2(u.p[1], wAr[4*i+1], a1);
            a0 = fdot2(u.p[2], wAr[4*i+2], a0);
            a1 = fdot2(u.p[3], wAr[4*i+3], a1);
            c0 = fdot2(u.p[0], wBr[4*i+0], c0);
            c1 = fdot2(u.p[1], wBr[4*i+1], c1);
            c0 = fdot2(u.p[2], wBr[4*i+2], c0);
            c1 = fdot2(u.p[3], wBr[4*i+3], c1);
        }
        {   // chunk 11: A from regs, B from LDS cid 4
            H8U u; u.v = *reinterpret_cast<const half8_t*>(hb + 8 * 11);
            H8U wc; wc.u4 = myW[4];
            a0 = fdot2(u.p[0], wAr[44], a0);
            a1 = fdot2(u.p[1], wAr[45], a1);
            a0 = fdot2(u.p[2], wAr[46], a0);
            a1 = fdot2(u.p[3], wAr[47], a1);
            c0 = fdot2(u.p[0], wc.p[0], c0);
            c1 = fdot2(u.p[1], wc.p[1], c1);
            c0 = fdot2(u.p[2], wc.p[2], c0);
            c1 = fdot2(u.p[3], wc.p[3], c1);
        }
#pragma unroll
        for (int i = 12; i < 16; ++i) {             // chunks 12..15: A cid i-12, B cid i-7
            H8U u; u.v = *reinterpret_cast<const half8_t*>(hb + 8 * i);
            H8U wa; wa.u4 = myW[i - 12];
            H8U wc; wc.u4 = myW[i - 7];
            a0 = fdot2(u.p[0], wa.p[0], a0);
            a1 = fdot2(u.p[1], wa.p[1], a1);
            a0 = fdot2(u.p[2], wa.p[2], a0);
            a1 = fdot2(u.p[3], wa.p[3], a1);
            c0 = fdot2(u.p[0], wc.p[0], c0);
            c1 = fdot2(u.p[1], wc.p[1], c1);
            c0 = fdot2(u.p[2], wc.p[2], c0);
            c1 = fdot2(u.p[3], wc.p[3], c1);
        }

        const float sA = quad_sum(a0 + a1);
        const float sB = quad_sum(c0 + c1);

        if (q == 0) {
            hA = fast_tanh(sA + (float)xv[0]);
            hB = fast_tanh(sB + (float)xv[1]);
            half2_t hw; hw[0] = (_Float16)hA; hw[1] = (_Float16)hB;
            *reinterpret_cast<half2_t*>((t & 1) ? wp0 : wp1) = hw;   // write buffer (t+1)&1
        }
        __syncthreads();
    }

    // ---- Epilogue: out[b] = sum_j h_j * fcw_j + fcb ----
    float partial = (q == 0) ? (hA * fcwA + hB * fcwB) : 0.f;
#pragma unroll
    for (int off = 32; off >= 1; off >>= 1)
        partial += __shfl_down(partial, off, 64);
    if ((tid & 63) == 0) red[tid >> 6] = partial;
    __syncthreads();
    if (tid == 0) {
        float s = 0.f;
#pragma unroll
        for (int w = 0; w < 16; ++w) s += red[w];
        out[b] = s + fcb[0];
    }
}

// ============================= fused fallback (K=576, unchanged) =============================
#define F_RP   216          // reg pairs: k in [0,432)
#define F_RC   54
#define F_LC   18           // LDS chunks: k in [432,576)
#define F_LSTR 19
#define F_LDSW_BYTES (512 * F_LSTR * 16)          // 155648
#define F_HBUF_OFF   F_LDSW_BYTES
#define F_HBUF_ELEMS 640                          // [0,512)=h, [512,576)=x_t
#define F_RED_OFF    (F_HBUF_OFF + 2 * F_HBUF_ELEMS * 2)
#define F_SMEM_BYTES (F_RED_OFF + 64)             // ~158.2 KB

__global__ __attribute__((amdgpu_flat_work_group_size(NTH, NTH), amdgpu_waves_per_eu(2, 2)))
void rnn_fused(const float* __restrict__ x, const float* __restrict__ Wxh,
               const float* __restrict__ Whh, const float* __restrict__ bias,
               const float* __restrict__ fcw, const float* __restrict__ fcb,
               float* __restrict__ out)
{
    extern __shared__ char smem[];
    uint4*    ldsW = reinterpret_cast<uint4*>(smem);
    _Float16* hbuf = reinterpret_cast<_Float16*>(smem + F_HBUF_OFF);
    float*    red  = reinterpret_cast<float*>(smem + F_RED_OFF);

    const int j = threadIdx.x;
    const int b = blockIdx.x;

    half2_t wreg[F_RP];
#pragma unroll
    for (int p = 0; p < F_RP; ++p) {
        const int k = 2 * p;
        half2_t w;
        w[0] = (_Float16)Whh[(size_t)k * HDIM + j];
        w[1] = (_Float16)Whh[(size_t)(k + 1) * HDIM + j];
        wreg[p] = w;
    }
#pragma unroll
    for (int cc = 0; cc < F_LC; ++cc) {
        H8U u;
#pragma unroll
        for (int qq = 0; qq < 4; ++qq) {
            const int k0 = 432 + 8 * cc + 2 * qq;
            const int k1 = k0 + 1;
            half2_t w;
            w[0] = (_Float16)(k0 < HDIM ? Whh[(size_t)k0 * HDIM + j]
                                        : Wxh[(size_t)(k0 - HDIM) * HDIM + j]);
            w[1] = (_Float16)(k1 < HDIM ? Whh[(size_t)k1 * HDIM + j]
                                        : Wxh[(size_t)(k1 - HDIM) * HDIM + j]);
            u.p[qq] = w;
        }
        ldsW[j * F_LSTR + cc] = u.u4;
    }

    const float bj   = bias[j];
    const float fcwj = fcw[j];

    hbuf[j] = (_Float16)0.0f;
    if (j < IDIM) hbuf[HDIM + j] = (_Float16)x[((size_t)b * TSTEPS + 0) * IDIM + j];
    __syncthreads();

    float hval = 0.0f;
    for (int t = 0; t < TSTEPS; ++t) {
        const int cur = t & 1;
        const int nxt = cur ^ 1;
        const _Float16* hb = hbuf + cur * F_HBUF_ELEMS;

        float xv = 0.0f;
        const bool do_x = (j < IDIM) && (t + 1 < TSTEPS);
        if (do_x) xv = x[((size_t)b * TSTEPS + (t + 1)) * IDIM + j];

        float a0 = bj, a1 = 0.0f, a2 = 0.0f, a3 = 0.0f;
#pragma unroll
        for (int c = 0; c < F_RC; ++c) {
            H8U u;
            u.v = *reinterpret_cast<const half8_t*>(hb + 8 * c);
            a0 = fdot2(u.p[0], wreg[4 * c + 0], a0);
            a1 = fdot2(u.p[1], wreg[4 * c + 1], a1);
            a2 = fdot2(u.p[2], wreg[4 * c + 2], a2);
            a3 = fdot2(u.p[3], wreg[4 * c + 3], a3);
        }
#pragma unroll
        for (int cc = 0; cc < F_LC; ++cc) {
            H8U u, w;
            u.v  = *reinterpret_cast<const half8_t*>(hb + 8 * (F_RC + cc));
            w.u4 = ldsW[j * F_LSTR + cc];
            a0 = fdot2(u.p[0], w.p[0], a0);
            a1 = fdot2(u.p[1], w.p[1], a1);
            a2 = fdot2(u.p[2], w.p[2], a2);
            a3 = fdot2(u.p[3], w.p[3], a3);
        }
        hval = fast_tanh((a0 + a1) + (a2 + a3));

        hbuf[nxt * F_HBUF_ELEMS + j] = (_Float16)hval;
        if (do_x) hbuf[nxt * F_HBUF_ELEMS + HDIM + j] = (_Float16)xv;
        __syncthreads();
    }

    float partial = hval * fcwj;
#pragma unroll
    for (int off = 32; off >= 1; off >>= 1)
        partial += __shfl_down(partial, off, 64);
    if ((j & 63) == 0) red[j >> 6] = partial;
    __syncthreads();
    if (j == 0) {
        float s = 0.0f;
#pragma unroll
        for (int w = 0; w < 8; ++w) s += red[w];
        out[b] = s + fcb[0];
    }
}

// ============================= host =============================
extern "C" void kernel_launch(void* const* d_in, const int* in_sizes, int n_in,
                              void* d_out, int out_size, void* d_ws, size_t ws_size,
                              hipStream_t stream) {
    const float* x    = (const float*)d_in[0];
    const float* Wxh  = (const float*)d_in[1];
    const float* Whh  = (const float*)d_in[2];
    const float* bias = (const float*)d_in[3];
    const float* fcw  = (const float*)d_in[4];
    const float* fcb  = (const float*)d_in[5];
    float* out = (float*)d_out;

    const size_t xh_bytes = (size_t)BATCH * TSTEPS * HDIM * sizeof(_Float16);  // 134 MB
    if (ws_size >= xh_bytes) {
        hipFuncSetAttribute(reinterpret_cast<const void*>(rnn_quad),
                            hipFuncAttributeMaxDynamicSharedMemorySize, Q_SMEM_BYTES);
        _Float16* xh = (_Float16*)d_ws;
        xh_gemm<<<(BATCH * TSTEPS) / XH_ROWS, NTH, 0, stream>>>(x, Wxh, bias, xh);
        rnn_quad<<<BATCH, NTH2, Q_SMEM_BYTES, stream>>>(xh, Whh, fcw, fcb, out);
    } else {
        hipFuncSetAttribute(reinterpret_cast<const void*>(rnn_fused),
                            hipFuncAttributeMaxDynamicSharedMemorySize, F_SMEM_BYTES);
        rnn_fused<<<BATCH, NTH, F_SMEM_BYTES, stream>>>(x, Wxh, Whh, bias, fcw, fcb, out);
    }
}

// Round 3
// 1242.673 us; speedup vs baseline: 1.1463x; 1.1169x over previous
//
#include <hip/hip_runtime.h>

// Problem: B=256, T=512, I=64, H=512.  h_t = tanh(x_t@Wxh + b + h@Whh); out = h_T@fc_w.T + fc_b
//
// rnn_k4 (this round): 1 batch row per block, 512 threads = PROVEN no-spill envelope
// (512thr + waves_per_eu(2,2) gave VGPR=128, WRITE_SIZE=8KB in rnn_split; the 1024-thr
// config capped arch VGPRs at 64 and spilled 86 regs -> 88 MB scratch writes, twice).
//   thread = (q = tid&3 -> K-quarter [128q,128q+128), c = tid>>2 -> cols 4c..4c+3)
//   Weights: 4 cols x 128 k = 256 half2/thread: 192 in regs (48/col), 64 in LDS
//            (4 chunks/col, thread-major stride 17 uint4 = 272B -> conflict-free b128).
//   h buffer: fp16, elem k at byte 288*(k>>7) + 2*(k&127)  (32B skew per K-quarter region)
//            -> per-wave h-read = 4 distinct 16B addrs (one per q), broadcast to 16 lanes,
//            conflict-free, immediate offsets.
//   Reduction: 4 accumulator-pairs -> 4 quad_sums (DPP, VALU-only); lane q writes col 4c+q.
//   1 barrier/step.  LDS instrs/CU-step: 128 h + 128 w (vs 256+144 at 1024thr).

#define BATCH    256
#define TSTEPS   512
#define IDIM     64
#define HDIM     512
#define NTH      512

typedef _Float16 half2_t __attribute__((ext_vector_type(2)));
typedef _Float16 half8_t __attribute__((ext_vector_type(8)));

union H8U {
    half8_t v;
    half2_t p[4];
    uint4   u4;
};

__device__ __forceinline__ float fdot2(half2_t a, half2_t b, float c) {
#if __has_builtin(__builtin_amdgcn_fdot2)
    return __builtin_amdgcn_fdot2(a, b, c, false);
#else
    return c + (float)a[0] * (float)b[0] + (float)a[1] * (float)b[1];
#endif
}

__device__ __forceinline__ float fast_tanh(float x) {
    float e = __builtin_amdgcn_exp2f(x * 2.88539008177792681472f);
    return 1.0f - 2.0f * __builtin_amdgcn_rcpf(e + 1.0f);
}

// sum over the 4 lanes of each quad (q = lane&3), VALU-only (no LDS, no barrier)
__device__ __forceinline__ float quad_sum(float x) {
    union { float f; int i; } a, b;
    a.f = x;
    b.i = __builtin_amdgcn_update_dpp(0, a.i, 0xB1, 0xF, 0xF, true); // quad_perm [1,0,3,2]
    a.f += b.f;
    b.i = __builtin_amdgcn_update_dpp(0, a.i, 0x4E, 0xF, 0xF, true); // quad_perm [2,3,0,1]
    a.f += b.f;
    return a.f;
}

// ============================= xh precompute (unchanged this round) =============================
#define XH_ROWS 16
__global__ __launch_bounds__(NTH, 4)
void xh_gemm(const float* __restrict__ x, const float* __restrict__ Wxh,
             const float* __restrict__ bias, _Float16* __restrict__ xh)
{
    const int j = threadIdx.x;
    const size_t r0 = (size_t)blockIdx.x * XH_ROWS;
    float wcol[IDIM];
#pragma unroll
    for (int i = 0; i < IDIM; ++i) wcol[i] = Wxh[(size_t)i * HDIM + j];
    const float bj = bias[j];
#pragma unroll
    for (int r = 0; r < XH_ROWS; ++r) {
        const float* xr = x + (r0 + r) * IDIM;   // wave-uniform address -> s_loads
        float acc = bj;
#pragma unroll
        for (int i = 0; i < IDIM; ++i) acc += xr[i] * wcol[i];
        xh[(r0 + r) * HDIM + j] = (_Float16)acc;
    }
}

// ============================= k4 RNN: 512 thr, 4-way K split, 4 cols/thread ==================
#define K4_RP      48                    // reg k-pairs per col (k 0..95 of slice)
#define K4_STR     17                    // uint4 stride per thread (16 chunks + 1 pad)
#define K4_W_BYTES (NTH * K4_STR * 16)   // 139264
#define K4_HB_OFF   K4_W_BYTES
#define K4_HB_STRIDE 1152                // 4x(256B data + 32B skew) rounded
#define K4_RED_OFF  (K4_HB_OFF + 2 * K4_HB_STRIDE)
#define K4_SMEM_BYTES (K4_RED_OFF + 64)  // 141696 (< 160 KiB -> 1 block/CU)

__global__ __attribute__((amdgpu_flat_work_group_size(NTH, NTH), amdgpu_waves_per_eu(2, 2)))
void rnn_k4(const _Float16* __restrict__ xh,   // (B*T, H) fp16, bias folded in
            const float* __restrict__ Whh,     // (H,H)
            const float* __restrict__ fcw,     // (1,H)
            const float* __restrict__ fcb,     // (1)
            float* __restrict__ out)           // (B,1)
{
    extern __shared__ char smem[];
    uint4* ldsW = reinterpret_cast<uint4*>(smem);
    float* red  = reinterpret_cast<float*>(smem + K4_RED_OFF);

    const int tid   = threadIdx.x;
    const int q     = tid & 3;          // K-quarter
    const int c     = tid >> 2;         // [0,128): column group
    const int j0    = 4 * c;            // first of 4 cols
    const int kbase = 128 * q;
    const int b     = blockIdx.x;

    // ---- prologue: weights for cols j0..j0+3, rows [kbase, kbase+128) ----
    half2_t wr0[K4_RP], wr1[K4_RP], wr2[K4_RP], wr3[K4_RP];
    uint4*  myW = ldsW + tid * K4_STR;   // 272B stride: bank(l)=4l mod 32 -> conflict-free b128
#pragma unroll
    for (int p = 0; p < K4_RP; ++p) {
        const float4 f0 = *reinterpret_cast<const float4*>(Whh + (size_t)(kbase + 2 * p) * HDIM + j0);
        const float4 f1 = *reinterpret_cast<const float4*>(Whh + (size_t)(kbase + 2 * p + 1) * HDIM + j0);
        half2_t w;
        w[0] = (_Float16)f0.x; w[1] = (_Float16)f1.x; wr0[p] = w;
        w[0] = (_Float16)f0.y; w[1] = (_Float16)f1.y; wr1[p] = w;
        w[0] = (_Float16)f0.z; w[1] = (_Float16)f1.z; wr2[p] = w;
        w[0] = (_Float16)f0.w; w[1] = (_Float16)f1.w; wr3[p] = w;
    }
#pragma unroll
    for (int cc = 0; cc < 4; ++cc) {     // k in [kbase+96, kbase+128): 4 chunks per col in LDS
        H8U t0, t1, t2, t3;
#pragma unroll
        for (int e = 0; e < 4; ++e) {
            const int k = kbase + 96 + 8 * cc + 2 * e;
            const float4 f0 = *reinterpret_cast<const float4*>(Whh + (size_t)k * HDIM + j0);
            const float4 f1 = *reinterpret_cast<const float4*>(Whh + (size_t)(k + 1) * HDIM + j0);
            half2_t w;
            w[0] = (_Float16)f0.x; w[1] = (_Float16)f1.x; t0.p[e] = w;
            w[0] = (_Float16)f0.y; w[1] = (_Float16)f1.y; t1.p[e] = w;
            w[0] = (_Float16)f0.z; w[1] = (_Float16)f1.z; t2.p[e] = w;
            w[0] = (_Float16)f0.w; w[1] = (_Float16)f1.w; t3.p[e] = w;
        }
        myW[cc]      = t0.u4;            // col 0: cids 0..3
        myW[4 + cc]  = t1.u4;            // col 1: cids 4..7
        myW[8 + cc]  = t2.u4;            // col 2: cids 8..11
        myW[12 + cc] = t3.u4;            // col 3: cids 12..15
    }

    // h buffers: elem k lives at byte 288*(k>>7) + 2*(k&127); read base for slice q = +288q
    const char* hb0c = smem + K4_HB_OFF + 288 * q;
    const char* hb1c = hb0c + K4_HB_STRIDE;
    const int   jw   = j0 + q;                       // this lane's output column
    const int   wbyte = 2 * jw + 32 * (jw >> 7);     // matches read layout
    _Float16* wp0 = reinterpret_cast<_Float16*>(smem + K4_HB_OFF + wbyte);
    _Float16* wp1 = reinterpret_cast<_Float16*>(smem + K4_HB_OFF + K4_HB_STRIDE + wbyte);

    const float fcwj = fcw[jw];
    const _Float16* xhp = xh + (size_t)b * TSTEPS * HDIM + jw;

    // zero both h buffers (2*1152 B = 144 uint4)
    if (tid < 144) {
        uint4 z; z.x = z.y = z.z = z.w = 0u;
        reinterpret_cast<uint4*>(smem + K4_HB_OFF)[tid] = z;
    }
    __syncthreads();

    float hlast = 0.f;
#pragma unroll 1
    for (int t = 0; t < TSTEPS; ++t) {
        const _Float16* hb = reinterpret_cast<const _Float16*>((t & 1) ? hb1c : hb0c);
        const float xv = (float)*xhp;    // xh[t][jw]
        xhp += HDIM;

        float a0 = 0.f, b0 = 0.f, a1 = 0.f, b1 = 0.f;
        float a2 = 0.f, b2 = 0.f, a3 = 0.f, b3 = 0.f;
#pragma unroll
        for (int i = 0; i < 12; ++i) {   // chunks 0..11: all 4 cols from regs
            H8U u; u.v = *reinterpret_cast<const half8_t*>(hb + 8 * i);
            a0 = fdot2(u.p[0], wr0[4*i+0], a0); b0 = fdot2(u.p[1], wr0[4*i+1], b0);
            a0 = fdot2(u.p[2], wr0[4*i+2], a0); b0 = fdot2(u.p[3], wr0[4*i+3], b0);
            a1 = fdot2(u.p[0], wr1[4*i+0], a1); b1 = fdot2(u.p[1], wr1[4*i+1], b1);
            a1 = fdot2(u.p[2], wr1[4*i+2], a1); b1 = fdot2(u.p[3], wr1[4*i+3], b1);
            a2 = fdot2(u.p[0], wr2[4*i+0], a2); b2 = fdot2(u.p[1], wr2[4*i+1], b2);
            a2 = fdot2(u.p[2], wr2[4*i+2], a2); b2 = fdot2(u.p[3], wr2[4*i+3], b2);
            a3 = fdot2(u.p[0], wr3[4*i+0], a3); b3 = fdot2(u.p[1], wr3[4*i+1], b3);
            a3 = fdot2(u.p[2], wr3[4*i+2], a3); b3 = fdot2(u.p[3], wr3[4*i+3], b3);
        }
#pragma unroll
        for (int cc = 0; cc < 4; ++cc) { // chunks 12..15: weights from LDS
            H8U u; u.v = *reinterpret_cast<const half8_t*>(hb + 8 * (12 + cc));
            H8U w0; w0.u4 = myW[cc];
            H8U w1; w1.u4 = myW[4 + cc];
            H8U w2; w2.u4 = myW[8 + cc];
            H8U w3; w3.u4 = myW[12 + cc];
            a0 = fdot2(u.p[0], w0.p[0], a0); b0 = fdot2(u.p[1], w0.p[1], b0);
            a0 = fdot2(u.p[2], w0.p[2], a0); b0 = fdot2(u.p[3], w0.p[3], b0);
            a1 = fdot2(u.p[0], w1.p[0], a1); b1 = fdot2(u.p[1], w1.p[1], b1);
            a1 = fdot2(u.p[2], w1.p[2], a1); b1 = fdot2(u.p[3], w1.p[3], b1);
            a2 = fdot2(u.p[0], w2.p[0], a2); b2 = fdot2(u.p[1], w2.p[1], b2);
            a2 = fdot2(u.p[2], w2.p[2], a2); b2 = fdot2(u.p[3], w2.p[3], b2);
            a3 = fdot2(u.p[0], w3.p[0], a3); b3 = fdot2(u.p[1], w3.p[1], b3);
            a3 = fdot2(u.p[2], w3.p[2], a3); b3 = fdot2(u.p[3], w3.p[3], b3);
        }

        const float s0 = quad_sum(a0 + b0);
        const float s1 = quad_sum(a1 + b1);
        const float s2 = quad_sum(a2 + b2);
        const float s3 = quad_sum(a3 + b3);

        // lane q takes col j0+q; all lanes active (no serialization)
        const float sq = (q & 2) ? ((q & 1) ? s3 : s2) : ((q & 1) ? s1 : s0);
        const float h  = fast_tanh(sq + xv);
        *((t & 1) ? wp0 : wp1) = (_Float16)h;    // write buffer (t+1)&1
        hlast = h;
        __syncthreads();
    }

    // ---- Epilogue: out[b] = sum_j h_j * fcw_j + fcb (each col owned by exactly one lane) ----
    float partial = hlast * fcwj;
#pragma unroll
    for (int off = 32; off >= 1; off >>= 1)
        partial += __shfl_down(partial, off, 64);
    if ((tid & 63) == 0) red[tid >> 6] = partial;
    __syncthreads();
    if (tid == 0) {
        float s = 0.f;
#pragma unroll
        for (int w = 0; w < 8; ++w) s += red[w];
        out[b] = s + fcb[0];
    }
}

// ============================= fused fallback (K=576, unchanged) =============================
#define F_RP   216          // reg pairs: k in [0,432)
#define F_RC   54
#define F_LC   18           // LDS chunks: k in [432,576)
#define F_LSTR 19
#define F_LDSW_BYTES (512 * F_LSTR * 16)          // 155648
#define F_HBUF_OFF   F_LDSW_BYTES
#define F_HBUF_ELEMS 640                          // [0,512)=h, [512,576)=x_t
#define F_RED_OFF    (F_HBUF_OFF + 2 * F_HBUF_ELEMS * 2)
#define F_SMEM_BYTES (F_RED_OFF + 64)             // ~158.2 KB

__global__ __attribute__((amdgpu_flat_work_group_size(NTH, NTH), amdgpu_waves_per_eu(2, 2)))
void rnn_fused(const float* __restrict__ x, const float* __restrict__ Wxh,
               const float* __restrict__ Whh, const float* __restrict__ bias,
               const float* __restrict__ fcw, const float* __restrict__ fcb,
               float* __restrict__ out)
{
    extern __shared__ char smem[];
    uint4*    ldsW = reinterpret_cast<uint4*>(smem);
    _Float16* hbuf = reinterpret_cast<_Float16*>(smem + F_HBUF_OFF);
    float*    red  = reinterpret_cast<float*>(smem + F_RED_OFF);

    const int j = threadIdx.x;
    const int b = blockIdx.x;

    half2_t wreg[F_RP];
#pragma unroll
    for (int p = 0; p < F_RP; ++p) {
        const int k = 2 * p;
        half2_t w;
        w[0] = (_Float16)Whh[(size_t)k * HDIM + j];
        w[1] = (_Float16)Whh[(size_t)(k + 1) * HDIM + j];
        wreg[p] = w;
    }
#pragma unroll
    for (int cc = 0; cc < F_LC; ++cc) {
        H8U u;
#pragma unroll
        for (int qq = 0; qq < 4; ++qq) {
            const int k0 = 432 + 8 * cc + 2 * qq;
            const int k1 = k0 + 1;
            half2_t w;
            w[0] = (_Float16)(k0 < HDIM ? Whh[(size_t)k0 * HDIM + j]
                                        : Wxh[(size_t)(k0 - HDIM) * HDIM + j]);
            w[1] = (_Float16)(k1 < HDIM ? Whh[(size_t)k1 * HDIM + j]
                                        : Wxh[(size_t)(k1 - HDIM) * HDIM + j]);
            u.p[qq] = w;
        }
        ldsW[j * F_LSTR + cc] = u.u4;
    }

    const float bj   = bias[j];
    const float fcwj = fcw[j];

    hbuf[j] = (_Float16)0.0f;
    if (j < IDIM) hbuf[HDIM + j] = (_Float16)x[((size_t)b * TSTEPS + 0) * IDIM + j];
    __syncthreads();

    float hval = 0.0f;
    for (int t = 0; t < TSTEPS; ++t) {
        const int cur = t & 1;
        const int nxt = cur ^ 1;
        const _Float16* hb = hbuf + cur * F_HBUF_ELEMS;

        float xv = 0.0f;
        const bool do_x = (j < IDIM) && (t + 1 < TSTEPS);
        if (do_x) xv = x[((size_t)b * TSTEPS + (t + 1)) * IDIM + j];

        float a0 = bj, a1 = 0.0f, a2 = 0.0f, a3 = 0.0f;
#pragma unroll
        for (int c = 0; c < F_RC; ++c) {
            H8U u;
            u.v = *reinterpret_cast<const half8_t*>(hb + 8 * c);
            a0 = fdot2(u.p[0], wreg[4 * c + 0], a0);
            a1 = fdot2(u.p[1], wreg[4 * c + 1], a1);
            a2 = fdot2(u.p[2], wreg[4 * c + 2], a2);
            a3 = fdot2(u.p[3], wreg[4 * c + 3], a3);
        }
#pragma unroll
        for (int cc = 0; cc < F_LC; ++cc) {
            H8U u, w;
            u.v  = *reinterpret_cast<const half8_t*>(hb + 8 * (F_RC + cc));
            w.u4 = ldsW[j * F_LSTR + cc];
            a0 = fdot2(u.p[0], w.p[0], a0);
            a1 = fdot2(u.p[1], w.p[1], a1);
            a2 = fdot2(u.p[2], w.p[2], a2);
            a3 = fdot2(u.p[3], w.p[3], a3);
        }
        hval = fast_tanh((a0 + a1) + (a2 + a3));

        hbuf[nxt * F_HBUF_ELEMS + j] = (_Float16)hval;
        if (do_x) hbuf[nxt * F_HBUF_ELEMS + HDIM + j] = (_Float16)xv;
        __syncthreads();
    }

    float partial = hval * fcwj;
#pragma unroll
    for (int off = 32; off >= 1; off >>= 1)
        partial += __shfl_down(partial, off, 64);
    if ((j & 63) == 0) red[j >> 6] = partial;
    __syncthreads();
    if (j == 0) {
        float s = 0.0f;
#pragma unroll
        for (int w = 0; w < 8; ++w) s += red[w];
        out[b] = s + fcb[0];
    }
}

// ============================= host =============================
extern "C" void kernel_launch(void* const* d_in, const int* in_sizes, int n_in,
                              void* d_out, int out_size, void* d_ws, size_t ws_size,
                              hipStream_t stream) {
    const float* x    = (const float*)d_in[0];
    const float* Wxh  = (const float*)d_in[1];
    const float* Whh  = (const float*)d_in[2];
    const float* bias = (const float*)d_in[3];
    const float* fcw  = (const float*)d_in[4];
    const float* fcb  = (const float*)d_in[5];
    float* out = (float*)d_out;

    const size_t xh_bytes = (size_t)BATCH * TSTEPS * HDIM * sizeof(_Float16);  // 134 MB
    if (ws_size >= xh_bytes) {
        hipFuncSetAttribute(reinterpret_cast<const void*>(rnn_k4),
                            hipFuncAttributeMaxDynamicSharedMemorySize, K4_SMEM_BYTES);
        _Float16* xh = (_Float16*)d_ws;
        xh_gemm<<<(BATCH * TSTEPS) / XH_ROWS, NTH, 0, stream>>>(x, Wxh, bias, xh);
        rnn_k4<<<BATCH, NTH, K4_SMEM_BYTES, stream>>>(xh, Whh, fcw, fcb, out);
    } else {
        hipFuncSetAttribute(reinterpret_cast<const void*>(rnn_fused),
                            hipFuncAttributeMaxDynamicSharedMemorySize, F_SMEM_BYTES);
        rnn_fused<<<BATCH, NTH, F_SMEM_BYTES, stream>>>(x, Wxh, Whh, bias, fcw, fcb, out);
    }
}